// Round 3
// baseline (282.576 us; speedup 1.0000x reference)
//
#include <hip/hip_runtime.h>
#include <math.h>

#define BB 256
#define LL 500
#define EE 300
#define NROWS (BB * LL)      // 128000
#define NJ 18                // 3 (aw3) + 1 (cw3) + 5 (aw5) + 1 (cw5) + 7 (aw7) + 1 (cw7)
#define NC 75                // float4 chunks per row
#define OPJ 10               // outputs per wave-job
#define NJOBS 50             // jobs per batch (50*10 = 500, exact)
#define JPW 4                // jobs chained per wave
#define WROWS 16             // dot rows per job = OPJ + 6 halo

// ---------------------------------------------------------------------------
// R9: wave-independent jobs. R8 (77us) proved issue-count fixes (DPP reduce,
// counted vmcnt) buy only their arithmetic share (~12us); VALUBusy stayed
// ~23% => the cost is PHASE LOCKSTEP: 4 waves barrier-synced per tile, grid
// exactly resident, so every wave stalls on the same ds_read chains / vmcnt /
// barrier simultaneously and nothing fills the holes. R9 keeps the proven
// 16-lane x 4-row mapping + DPP reduce + full x prefetch + next-job prefetch
// into the same regs, but each WAVE owns 16 rows -> 10 outputs (private +-3
// halo) and hands dots to its epilogue through a PER-WAVE LDS patch needing
// only lgkmcnt(0) (same-wave LDS coherence) -- ZERO barriers in the main
// loop. 12800 free-running waves (50/CU oversubscribed, 1024 blocks) drift
// out of phase and hide each other's latency. Cost: +37% halo FMA (14us
// chip floor, still under the ~22us LDS-pipe floor). R7 lesson kept: x stays
// in registers.
// ---------------------------------------------------------------------------

__device__ __forceinline__ float red16(float v) {
    // sum across each aligned 16-lane group, VALU-only (no LDS pipe)
    int t;
    t = __builtin_amdgcn_update_dpp(0, __float_as_int(v), 0xB1, 0xF, 0xF, true);  // quad_perm [1,0,3,2]
    v += __int_as_float(t);
    t = __builtin_amdgcn_update_dpp(0, __float_as_int(v), 0x4E, 0xF, 0xF, true);  // quad_perm [2,3,0,1]
    v += __int_as_float(t);
    t = __builtin_amdgcn_update_dpp(0, __float_as_int(v), 0x124, 0xF, 0xF, true); // row_ror:4
    v += __int_as_float(t);
    t = __builtin_amdgcn_update_dpp(0, __float_as_int(v), 0x128, 0xF, 0xF, true); // row_ror:8
    v += __int_as_float(t);
    return v;
}

__device__ __forceinline__ void lds_fence_barrier() {
    // publish own LDS ops, cross the barrier, leave global loads in flight
    asm volatile("s_waitcnt lgkmcnt(0)" ::: "memory");
    __builtin_amdgcn_s_barrier();
    asm volatile("" ::: "memory");
}

__global__ __launch_bounds__(256) void fused_kernel(
    const float* __restrict__ x,
    const float* __restrict__ aw3, const float* __restrict__ ab3,
    const float* __restrict__ cw3, const float* __restrict__ cb3,
    const float* __restrict__ aw5, const float* __restrict__ ab5,
    const float* __restrict__ cw5, const float* __restrict__ cb5,
    const float* __restrict__ aw7, const float* __restrict__ ab7,
    const float* __restrict__ cw7, const float* __restrict__ cb7,
    float* __restrict__ out)
{
    __shared__ float4 wlds[NJ * NC];             // 21.6 KB, layout [d][75]
    __shared__ float dlds[4][WROWS][NJ + 1];     // per-wave private patch, 4.9 KB

    const int tid = threadIdx.x;

    // ---- cooperative weight staging (oldest vmem in queue: the ds_writes'
    //      vmcnt waits retire ONLY these, leaving x loads in flight) ----
    {
        const float4* s3a = (const float4*)aw3;   // 225
        const float4* s3c = (const float4*)cw3;   // 75
        const float4* s5a = (const float4*)aw5;   // 375
        const float4* s5c = (const float4*)cw5;   // 75
        const float4* s7a = (const float4*)aw7;   // 525
        const float4* s7c = (const float4*)cw7;   // 75
        for (int i = tid; i < 225; i += 256) wlds[i]        = s3a[i];
        for (int i = tid; i < 75;  i += 256) wlds[225 + i]  = s3c[i];
        for (int i = tid; i < 375; i += 256) wlds[300 + i]  = s5a[i];
        for (int i = tid; i < 75;  i += 256) wlds[675 + i]  = s5c[i];
        for (int i = tid; i < 525; i += 256) wlds[750 + i]  = s7a[i];
        for (int i = tid; i < 75;  i += 256) wlds[1275 + i] = s7c[i];
    }

    const int batch = blockIdx.x >> 2;           // 4 blocks per batch
    const int sub   = blockIdx.x & 3;
    const int wave  = tid >> 6;                  // 0..3
    const int lane  = tid & 63;
    const int g     = lane >> 4;                 // 0..3 (group)
    const int j     = lane & 15;                 // 0..15 (lane in group)
    const int lr    = g * 4;                     // local row base (0,4,8,12)
    const int job0  = sub * 16 + wave * JPW;     // first job of this wave's chain

    const float* xbb = x + (size_t)batch * LL * EE;

    // ---- job-0 x prefetch: 20 float4/lane (clamped rows), stays in flight
    //      across the staging barrier ----
    float4 xall[5][4];
    if (job0 < NJOBS) {
        const int l0 = job0 * OPJ - 3;
#pragma unroll
        for (int rr = 0; rr < 4; ++rr) {
            const int l  = l0 + lr + rr;
            const int lc = l < 0 ? 0 : (l >= LL ? LL - 1 : l);
            const float4* xr = (const float4*)(xbb + (size_t)lc * EE);
#pragma unroll
            for (int k = 0; k < 5; ++k) {
                const int c = (k == 4) ? ((j < 11) ? (j + 64) : 74) : (j + 16 * k);
                xall[k][rr] = xr[c];
            }
        }
    }

    lds_fence_barrier();          // the ONLY barrier in the kernel
    if (job0 >= NJOBS) return;    // idle waves exit after staging duty

    float* dl = &dlds[wave][0][0];     // this wave's private patch, stride NJ+1

#pragma unroll 1
    for (int jj = 0; jj < JPW; ++jj) {
        const int job = job0 + jj;           // wave-uniform
        if (job >= NJOBS) break;
        const int l0 = job * OPJ - 3;

        float vf[4];
#pragma unroll
        for (int rr = 0; rr < 4; ++rr) {
            const int l = l0 + lr + rr;
            vf[rr] = (l >= 0 && l < LL) ? 1.0f : 0.0f;
        }

        float acc[NJ][4];
#pragma unroll
        for (int d = 0; d < NJ; ++d)
#pragma unroll
            for (int rr = 0; rr < 4; ++rr) acc[d][rr] = 0.0f;

#define COMPUTE(k, c)                                                               \
    {                                                                               \
        _Pragma("unroll")                                                           \
        for (int d = 0; d < NJ; ++d) {                                              \
            const float4 w = wlds[d * NC + (c)];                                    \
            acc[d][0] = fmaf(xall[k][0].w, w.w, fmaf(xall[k][0].z, w.z, fmaf(xall[k][0].y, w.y, fmaf(xall[k][0].x, w.x, acc[d][0])))); \
            acc[d][1] = fmaf(xall[k][1].w, w.w, fmaf(xall[k][1].z, w.z, fmaf(xall[k][1].y, w.y, fmaf(xall[k][1].x, w.x, acc[d][1])))); \
            acc[d][2] = fmaf(xall[k][2].w, w.w, fmaf(xall[k][2].z, w.z, fmaf(xall[k][2].y, w.y, fmaf(xall[k][2].x, w.x, acc[d][2])))); \
            acc[d][3] = fmaf(xall[k][3].w, w.w, fmaf(xall[k][3].z, w.z, fmaf(xall[k][3].y, w.y, fmaf(xall[k][3].x, w.x, acc[d][3])))); \
        }                                                                           \
    }

        COMPUTE(0, j)
        COMPUTE(1, j + 16)
        COMPUTE(2, j + 32)
        COMPUTE(3, j + 48)
        if (j < 11) {
            COMPUTE(4, j + 64)
        }
#undef COMPUTE

        // ---- issue next job's x loads into the same regs (last use above);
        //      they fly through the reduce + patch write + epilogue ----
        if (jj + 1 < JPW && job + 1 < NJOBS) {
            const int l0n = (job + 1) * OPJ - 3;
#pragma unroll
            for (int rr = 0; rr < 4; ++rr) {
                const int l  = l0n + lr + rr;
                const int lc = l < 0 ? 0 : (l >= LL ? LL - 1 : l);
                const float4* xr = (const float4*)(xbb + (size_t)lc * EE);
#pragma unroll
                for (int k = 0; k < 5; ++k) {
                    const int c = (k == 4) ? ((j < 11) ? (j + 64) : 74) : (j + 16 * k);
                    xall[k][rr] = xr[c];
                }
            }
        }

        // ---- VALU-only 16-lane reduction ----
#pragma unroll
        for (int d = 0; d < NJ; ++d)
#pragma unroll
            for (int rr = 0; rr < 4; ++rr) acc[d][rr] = red16(acc[d][rr]);

        // lane j == rr stores row lr+rr into the wave's private patch
#pragma unroll
        for (int rr = 0; rr < 4; ++rr) {
            if (j == rr) {
#pragma unroll
                for (int d = 0; d < NJ; ++d) dl[(lr + rr) * (NJ + 1) + d] = acc[d][rr] * vf[rr];
            }
        }

        // same-wave LDS visibility: counter wait only, NO barrier
        asm volatile("s_waitcnt lgkmcnt(0)" ::: "memory");

        // ---- epilogue: lanes 0..9 each produce all 3 branch outputs ----
        if (lane < OPJ) {
            const int c = lane + 3;              // local row of the center
            const int r = batch * LL + job * OPJ + lane;
            {
                float pre = 0.0f;
#pragma unroll
                for (int tp = 0; tp < 3; ++tp) pre += dl[(c + tp - 1) * (NJ + 1) + tp];
                const float s = 1.0f / (1.0f + expf(-(pre + ab3[0])));
                out[r] = tanhf(s * dl[c * (NJ + 1) + 3] + cb3[0]);
            }
            {
                float pre = 0.0f;
#pragma unroll
                for (int tp = 0; tp < 5; ++tp) pre += dl[(c + tp - 2) * (NJ + 1) + 4 + tp];
                const float s = 1.0f / (1.0f + expf(-(pre + ab5[0])));
                out[NROWS + r] = tanhf(s * dl[c * (NJ + 1) + 9] + cb5[0]);
            }
            {
                float pre = 0.0f;
#pragma unroll
                for (int tp = 0; tp < 7; ++tp) pre += dl[(c + tp - 3) * (NJ + 1) + 10 + tp];
                const float s = 1.0f / (1.0f + expf(-(pre + ab7[0])));
                out[2 * NROWS + r] = tanhf(s * dl[c * (NJ + 1) + 17] + cb7[0]);
            }
        }
        // next job's patch writes are same-wave, in-order on the LDS pipe:
        // they cannot pass this job's epilogue reads. No extra sync needed.
    }
}

extern "C" void kernel_launch(void* const* d_in, const int* in_sizes, int n_in,
                              void* d_out, int out_size, void* d_ws, size_t ws_size,
                              hipStream_t stream) {
    const float* x   = (const float*)d_in[0];
    const float* aw3 = (const float*)d_in[1];
    const float* ab3 = (const float*)d_in[2];
    const float* cw3 = (const float*)d_in[3];
    const float* cb3 = (const float*)d_in[4];
    const float* aw5 = (const float*)d_in[5];
    const float* ab5 = (const float*)d_in[6];
    const float* cw5 = (const float*)d_in[7];
    const float* cb5 = (const float*)d_in[8];
    const float* aw7 = (const float*)d_in[9];
    const float* ab7 = (const float*)d_in[10];
    const float* cw7 = (const float*)d_in[11];
    const float* cb7 = (const float*)d_in[12];

    float* out = (float*)d_out;  // [out3 | out5 | out7]

    // 256 batches x 4 blocks; block = 4 independent waves x 4 chained jobs
    // (64 job slots cover 50 jobs; surplus waves exit after staging duty)
    fused_kernel<<<BB * 4, 256, 0, stream>>>(
        x, aw3, ab3, cw3, cb3, aw5, ab5, cw5, cb5, aw7, ab7, cw7, cb7, out);
}